// Round 5
// baseline (522.794 us; speedup 1.0000x reference)
//
#include <hip/hip_runtime.h>

#define BB 16
#define DD 512
#define TT 4096
#define KK 1024

typedef _Float16 h16;
typedef __attribute__((ext_vector_type(8))) _Float16 half8;
typedef __attribute__((ext_vector_type(4))) float float4v;

// ---- ws layout (main path), bytes ----
// xth/xtl tiled: [b][tb(32)][dcb(16)][128][32] halfs -> 64 MiB per plane
// cbh/cbl tiled: [kb(8)][dcb(16)][128][32] halfs    -> 1 MiB per plane
#define XTH_OFF 0ull
#define XTL_OFF 67108864ull
#define CBH_OFF 134217728ull
#define CBL_OFF 135266304ull
#define CSQ_OFF 136314880ull
#define WS_NEED (136314880ull + 4096ull)

// ---------------------------------------------------------------------------
// csq[k] = sum_d cb[k][d]^2
// ---------------------------------------------------------------------------
__global__ void csq_kernel(const float* __restrict__ cb, float* __restrict__ csq) {
    int wave = threadIdx.x >> 6;
    int lane = threadIdx.x & 63;
    int row  = blockIdx.x * 4 + wave;
    const float* r = cb + (size_t)row * DD;
    float s = 0.f;
    #pragma unroll
    for (int i = 0; i < DD / 64; ++i) { float v = r[lane + i * 64]; s += v * v; }
    #pragma unroll
    for (int off = 32; off; off >>= 1) s += __shfl_down(s, off, 64);
    if (lane == 0) csq[row] = s;
}

// ---------------------------------------------------------------------------
// split x [B][D][T] fp32 -> tiled f16 planes [b][tb][dcb][128][32].
// ---------------------------------------------------------------------------
__global__ __launch_bounds__(256) void split_x_kernel(const float* __restrict__ x,
                                                      h16* __restrict__ xth,
                                                      h16* __restrict__ xtl) {
    __shared__ float xs[32][132];  // float4-stored rows, 16B-aligned stride
    const int tb = blockIdx.x, dcb = blockIdx.y, b = blockIdx.z;
    const int tid = threadIdx.x;
    const int t0 = tb * 128, d0 = dcb * 32;
    const float* xp = x + ((size_t)b * DD + d0) * TT + t0;
    #pragma unroll
    for (int j = 0; j < 4; ++j) {
        int i4 = tid + 256 * j;
        int dd = i4 >> 5, c4 = (i4 & 31) << 2;
        *(float4*)&xs[dd][c4] = *(const float4*)(xp + (size_t)dd * TT + c4);
    }
    __syncthreads();
    const int r = tid >> 1;              // t-local row of output
    const int ch = (tid & 1) * 16;       // d-half
    h16 hv[16], lv[16];
    #pragma unroll
    for (int i = 0; i < 16; ++i) {
        float v = xs[ch + i][r];
        h16 h = (h16)v;
        hv[i] = h;
        lv[i] = (h16)(v - (float)h);
    }
    size_t o = (((size_t)(b * 32 + tb) * 16) + dcb) * 4096 + (size_t)tid * 16;
    *(half8*)(xth + o)     = *(half8*)&hv[0];
    *(half8*)(xth + o + 8) = *(half8*)&hv[8];
    *(half8*)(xtl + o)     = *(half8*)&lv[0];
    *(half8*)(xtl + o + 8) = *(half8*)&lv[8];
}

// ---------------------------------------------------------------------------
// split cb [K][D] fp32 -> tiled f16 planes [kb][dcb][128][32]. No transpose.
// ---------------------------------------------------------------------------
__global__ __launch_bounds__(256) void split_cb_kernel(const float* __restrict__ cb,
                                                       h16* __restrict__ cbh,
                                                       h16* __restrict__ cbl) {
    const int kb = blockIdx.x >> 4, dcb = blockIdx.x & 15;
    const int tid = threadIdx.x;
    const float* cp = cb + ((size_t)kb * 128) * DD + dcb * 32;
    h16* oh = cbh + ((size_t)(kb * 16 + dcb)) * 4096;
    h16* ol = cbl + ((size_t)(kb * 16 + dcb)) * 4096;
    #pragma unroll
    for (int j = 0; j < 4; ++j) {
        int i4 = tid + 256 * j;
        int rr = i4 >> 3, c4 = (i4 & 7) << 2;
        float4 v = *(const float4*)(cp + (size_t)rr * DD + c4);
        float vv[4] = {v.x, v.y, v.z, v.w};
        h16 h[4], l[4];
        #pragma unroll
        for (int i = 0; i < 4; ++i) {
            h[i] = (h16)vv[i];
            l[i] = (h16)(vv[i] - (float)h[i]);
        }
        *(ushort4*)(oh + rr * 32 + c4) = *(ushort4*)h;
        *(ushort4*)(ol + rr * 32 + c4) = *(ushort4*)l;
    }
}

// ---------------------------------------------------------------------------
// fused f16x3-split MFMA GEMM + argmin + gather.
// score[t][k] = csq[k] - 2 * (xh.bh + xh.bl + xl.bh)
// v6: NO LDS STAGING. Evidence (v1..v5): wall == MFMA-pipe + LDS-pipe +
// waits, serialized by the barrier lockstep; neither HBM volume, LDS
// volume, occupancy, nor schedule moved dur. The tiled [128][32] layout
// makes each wave's MFMA fragment a contiguous coalesced 1 KiB global
// read -> load fragments DIRECTLY global->VGPR. B (2 MiB) is L2-resident;
// A-frag x4 in-block redundancy hits L1/L2. No barriers, no waitcnt
// choreography, no LDS pipe: compiler software-pipelines freely.
// Manual 2-deep register double-buffer (static even/odd sets).
// Per-acc MFMA order AhBh -> AhBl -> AlBh per dcb, dcb/k ascending:
// bit-identical to previous versions.
// ---------------------------------------------------------------------------
__global__ __launch_bounds__(512, 2) void mfma_argmin_kernel(
    const h16* __restrict__ xth, const h16* __restrict__ xtl,
    const h16* __restrict__ cbh, const h16* __restrict__ cbl,
    const float* __restrict__ csq, const float* __restrict__ cb,
    float* __restrict__ idx_f_out, float* __restrict__ out) {

    __shared__ float redv[4][128];
    __shared__ int   redi[4][128];

    const int tid = threadIdx.x;
    const int wid = tid >> 6, lane = tid & 63;
    const int wm = wid & 1;            // t-half of tile (0/1)
    const int wn = wid >> 1;           // k-quarter of 256-chunk (0..3)
    const int tb = blockIdx.x, b = blockIdx.y;
    const int t0 = tb * 128;
    const int c  = lane & 15;          // frag col
    const int q  = lane >> 4;          // frag quad

    const h16* aH = xth + ((size_t)(b * 32 + tb) * 16) * 4096;
    const h16* aL = xtl + ((size_t)(b * 32 + tb) * 16) * 4096;

    // per-lane fragment base offsets (in halfs)
    int abase[4], bbase[4];
    #pragma unroll
    for (int m = 0; m < 4; ++m)
        abase[m] = (wm * 64 + m * 16 + c) * 32 + q * 8;
    #pragma unroll
    for (int n = 0; n < 4; ++n) {
        int krow = wn * 64 + n * 16;             // 0..240, no c-carry across 128
        int hi = krow >> 7;                      // which kb half of the 256-chunk
        int lo = (krow & 127) + c;
        bbase[n] = hi * 65536 + lo * 32 + q * 8; // 65536 halfs per kb block
    }

    float best[16];
    int   bidx[16];
    #pragma unroll
    for (int i = 0; i < 16; ++i) { best[i] = 3.4e38f; bidx[i] = 0; }

    float4v acc[4][4];
    #pragma unroll
    for (int m = 0; m < 4; ++m)
        #pragma unroll
        for (int n = 0; n < 4; ++n)
            acc[m][n] = (float4v){0.f, 0.f, 0.f, 0.f};

    half8 Ah0[4], Al0[4], Bh0[4], Bl0[4];
    half8 Ah1[4], Al1[4], Bh1[4], Bl1[4];

    // gi = kci*16 + dcb ; A at dcb*4096 ; B at kci*131072 + dcb*4096
#define LOADSET(GI, S) do {                                                  \
        const size_t ao_ = (size_t)((GI) & 15) * 4096;                       \
        const size_t bo_ = (size_t)((GI) >> 4) * 131072 + ao_;               \
        _Pragma("unroll")                                                    \
        for (int m_ = 0; m_ < 4; ++m_) {                                     \
            Ah##S[m_] = *(const half8*)(aH + ao_ + abase[m_]);               \
            Al##S[m_] = *(const half8*)(aL + ao_ + abase[m_]);               \
        }                                                                    \
        _Pragma("unroll")                                                    \
        for (int n_ = 0; n_ < 4; ++n_) {                                     \
            Bh##S[n_] = *(const half8*)(cbh + bo_ + bbase[n_]);              \
            Bl##S[n_] = *(const half8*)(cbl + bo_ + bbase[n_]);              \
        }                                                                    \
    } while (0)

#define MFMASET(S) do {                                                      \
        _Pragma("unroll")                                                    \
        for (int n_ = 0; n_ < 4; ++n_)                                       \
            _Pragma("unroll")                                                \
            for (int m_ = 0; m_ < 4; ++m_)                                   \
                acc[m_][n_] = __builtin_amdgcn_mfma_f32_16x16x32_f16(        \
                    Ah##S[m_], Bh##S[n_], acc[m_][n_], 0, 0, 0);             \
        _Pragma("unroll")                                                    \
        for (int n_ = 0; n_ < 4; ++n_)                                       \
            _Pragma("unroll")                                                \
            for (int m_ = 0; m_ < 4; ++m_)                                   \
                acc[m_][n_] = __builtin_amdgcn_mfma_f32_16x16x32_f16(        \
                    Ah##S[m_], Bl##S[n_], acc[m_][n_], 0, 0, 0);             \
        _Pragma("unroll")                                                    \
        for (int n_ = 0; n_ < 4; ++n_)                                       \
            _Pragma("unroll")                                                \
            for (int m_ = 0; m_ < 4; ++m_)                                   \
                acc[m_][n_] = __builtin_amdgcn_mfma_f32_16x16x32_f16(        \
                    Al##S[m_], Bh##S[n_], acc[m_][n_], 0, 0, 0);             \
    } while (0)

#define FOLD(KCI) do {                                                       \
        _Pragma("unroll")                                                    \
        for (int n_ = 0; n_ < 4; ++n_) {                                     \
            int kg_ = (KCI) * 256 + wn * 64 + n_ * 16 + c;                   \
            float cq_ = csq[kg_];                                            \
            _Pragma("unroll")                                                \
            for (int m_ = 0; m_ < 4; ++m_)                                   \
                _Pragma("unroll")                                            \
                for (int r_ = 0; r_ < 4; ++r_) {                             \
                    float s_ = fmaf(-2.0f, acc[m_][n_][r_], cq_);            \
                    int slot_ = m_ * 4 + r_;                                 \
                    if (s_ < best[slot_]) { best[slot_] = s_; bidx[slot_] = kg_; } \
                }                                                            \
        }                                                                    \
        _Pragma("unroll")                                                    \
        for (int m_ = 0; m_ < 4; ++m_)                                       \
            _Pragma("unroll")                                                \
            for (int n_ = 0; n_ < 4; ++n_)                                   \
                acc[m_][n_] = (float4v){0.f, 0.f, 0.f, 0.f};                 \
    } while (0)

    LOADSET(0, 0);
    for (int gp = 0; gp < 31; ++gp) {
        const int gi = gp * 2;
        LOADSET(gi + 1, 1);
        MFMASET(0);                       // tile gi
        LOADSET(gi + 2, 0);
        MFMASET(1);                       // tile gi+1
        if ((gp & 7) == 7) FOLD(gp >> 3); // gi+1 in {15,31,47}
    }
    LOADSET(63, 1);
    MFMASET(0);                           // tile 62
    MFMASET(1);                           // tile 63
    FOLD(3);

#undef LOADSET
#undef MFMASET
#undef FOLD

    // reduce over the 16 frag columns (lanes sharing a t)
    #pragma unroll
    for (int slot = 0; slot < 16; ++slot) {
        float v = best[slot]; int i = bidx[slot];
        #pragma unroll
        for (int d = 1; d < 16; d <<= 1) {
            float pv = __shfl_xor(v, d);
            int   pi = __shfl_xor(i, d);
            if (pv < v || (pv == v && pi < i)) { v = pv; i = pi; }
        }
        if (c == 0) {
            int m = slot >> 2, r = slot & 3;
            int tl = wm * 64 + m * 16 + q * 4 + r;
            redv[wn][tl] = v; redi[wn][tl] = i;
        }
    }
    __syncthreads();
    if (tid < 128) {
        float v0 = redv[0][tid]; int i0 = redi[0][tid];
        #pragma unroll
        for (int gi = 1; gi < 4; ++gi) {
            float v1 = redv[gi][tid]; int i1 = redi[gi][tid];
            if (v1 < v0 || (v1 == v0 && i1 < i0)) { v0 = v1; i0 = i1; }
        }
        idx_f_out[(size_t)b * TT + t0 + tid] = (float)i0;
        redi[0][tid] = i0;                 // broadcast final index
    }
    __syncthreads();

    // fused gather: out[b][d][t0+tl] = cb[k][d]; 512 threads -> 128 d each
    const int tl = tid & 127, dg = tid >> 7;
    const int k = redi[0][tl];
    const float* row = cb + (size_t)k * DD + dg * 128;
    float* ob = out + ((size_t)b * DD + dg * 128) * TT + t0 + tl;
    #pragma unroll 4
    for (int i = 0; i < 32; ++i) {
        float4 v = *(const float4*)(row + i * 4);
        ob[(size_t)(i * 4 + 0) * TT] = v.x;
        ob[(size_t)(i * 4 + 1) * TT] = v.y;
        ob[(size_t)(i * 4 + 2) * TT] = v.z;
        ob[(size_t)(i * 4 + 3) * TT] = v.w;
    }
}

// ---------------------------------------------------------------------------
// fallback fp32 path + standalone gather (used only if ws too small)
// ---------------------------------------------------------------------------
__global__ void gather_kernel(const float* __restrict__ cb,
                              const float* __restrict__ idx_f,
                              float* __restrict__ out) {
    int b  = blockIdx.y;
    int t  = blockIdx.x * 256 + threadIdx.x;
    int d0 = blockIdx.z * (DD / 4);
    int k  = (int)idx_f[(size_t)b * TT + t];
    const float* row = cb + (size_t)k * DD;
    float* ob = out + (size_t)b * DD * TT + t;
    #pragma unroll 8
    for (int d = d0; d < d0 + DD / 4; ++d)
        ob[(size_t)d * TT] = row[d];
}

__global__ __launch_bounds__(256) void argmin_fp32_kernel(
    const float* __restrict__ x, const float* __restrict__ cb,
    const float* __restrict__ csq, float* __restrict__ idx_f_out) {

    __shared__ float xs[32][128];
    __shared__ float cs[32][132];

    const int tid = threadIdx.x;
    const int b = blockIdx.y;
    const int t_blk = blockIdx.x * 128;
    const int tq = tid & 15, kq = tid >> 4;
    const int t0 = tq * 8, k0 = kq * 8;
    const float* xb = x + (size_t)b * DD * TT;

    float best[8]; int bidx[8];
    #pragma unroll
    for (int i = 0; i < 8; ++i) { best[i] = 3.4e38f; bidx[i] = 0; }

    for (int kc = 0; kc < KK; kc += 128) {
        float acc[8][8];
        #pragma unroll
        for (int i = 0; i < 8; ++i)
            #pragma unroll
            for (int j = 0; j < 8; ++j) acc[i][j] = 0.f;
        for (int dc = 0; dc < DD; dc += 32) {
            __syncthreads();
            #pragma unroll
            for (int j = 0; j < 4; ++j) {
                int i4 = tid + 256 * j;
                int dd = i4 >> 5, tp = (i4 & 31) << 2;
                *(float4*)&xs[dd][tp] =
                    *(const float4*)(xb + (size_t)(dc + dd) * TT + t_blk + tp);
            }
            #pragma unroll
            for (int j = 0; j < 4; ++j) {
                int i4 = tid + 256 * j;
                int kk = i4 >> 3, dq = (i4 & 7) << 2;
                float4 v = *(const float4*)(cb + (size_t)(kc + kk) * DD + dc + dq);
                cs[dq + 0][kk] = v.x; cs[dq + 1][kk] = v.y;
                cs[dq + 2][kk] = v.z; cs[dq + 3][kk] = v.w;
            }
            __syncthreads();
            #pragma unroll 8
            for (int dd = 0; dd < 32; ++dd) {
                float a[8], bv[8];
                *(float4*)&a[0]  = *(const float4*)&xs[dd][t0];
                *(float4*)&a[4]  = *(const float4*)&xs[dd][t0 + 4];
                *(float4*)&bv[0] = *(const float4*)&cs[dd][k0];
                *(float4*)&bv[4] = *(const float4*)&cs[dd][k0 + 4];
                #pragma unroll
                for (int i = 0; i < 8; ++i)
                    #pragma unroll
                    for (int j = 0; j < 8; ++j)
                        acc[i][j] = fmaf(a[i], bv[j], acc[i][j]);
            }
        }
        #pragma unroll
        for (int j = 0; j < 8; ++j) {
            int kg = kc + k0 + j;
            float cq = csq[kg];
            #pragma unroll
            for (int i = 0; i < 8; ++i) {
                float s = cq - 2.0f * acc[i][j];
                if (s < best[i]) { best[i] = s; bidx[i] = kg; }
            }
        }
    }
    __syncthreads();
    float* rbest = &xs[0][0];
    int*   ridx  = (int*)&cs[0][0];
    #pragma unroll
    for (int i = 0; i < 8; ++i) {
        rbest[kq * 128 + t0 + i] = best[i];
        ridx [kq * 128 + t0 + i] = bidx[i];
    }
    __syncthreads();
    if (tid < 128) {
        float bv = rbest[tid]; int bi = ridx[tid];
        #pragma unroll
        for (int g = 1; g < 16; ++g) {
            float v = rbest[g * 128 + tid]; int ii = ridx[g * 128 + tid];
            if (v < bv || (v == bv && ii < bi)) { bv = v; bi = ii; }
        }
        idx_f_out[(size_t)b * TT + t_blk + tid] = (float)bi;
    }
}

extern "C" void kernel_launch(void* const* d_in, const int* in_sizes, int n_in,
                              void* d_out, int out_size, void* d_ws, size_t ws_size,
                              hipStream_t stream) {
    const float* x  = (const float*)d_in[0];
    const float* cb = (const float*)d_in[1];
    float* out   = (float*)d_out;
    float* idx_f = out + (size_t)BB * DD * TT;

    if (ws_size >= WS_NEED) {
        h16* xth = (h16*)((char*)d_ws + XTH_OFF);
        h16* xtl = (h16*)((char*)d_ws + XTL_OFF);
        h16* cbh = (h16*)((char*)d_ws + CBH_OFF);
        h16* cbl = (h16*)((char*)d_ws + CBL_OFF);
        float* csq = (float*)((char*)d_ws + CSQ_OFF);

        csq_kernel<<<KK / 4, 256, 0, stream>>>(cb, csq);
        split_cb_kernel<<<128, 256, 0, stream>>>(cb, cbh, cbl);
        split_x_kernel<<<dim3(TT / 128, DD / 32, BB), 256, 0, stream>>>(x, xth, xtl);
        mfma_argmin_kernel<<<dim3(TT / 128, BB), 512, 0, stream>>>(
            xth, xtl, cbh, cbl, csq, cb, idx_f, out);
    } else {
        float* csq = (float*)d_ws;
        csq_kernel<<<KK / 4, 256, 0, stream>>>(cb, csq);
        argmin_fp32_kernel<<<dim3(TT / 128, BB), 256, 0, stream>>>(x, cb, csq, idx_f);
        gather_kernel<<<dim3(TT / 256, BB, 4), 256, 0, stream>>>(cb, idx_f, out);
    }
}

// Round 6
// 484.646 us; speedup vs baseline: 1.0787x; 1.0787x over previous
//
#include <hip/hip_runtime.h>

#define BB 16
#define DD 512
#define TT 4096
#define KK 1024

typedef _Float16 h16;
typedef __attribute__((ext_vector_type(8))) _Float16 half8;
typedef __attribute__((ext_vector_type(4))) float float4v;

// ---- ws layout (main path), bytes ----
// xth/xtl tiled: [b][tb(32)][dcb(16)][128][32] halfs -> 64 MiB per plane
// cbh/cbl tiled: [kb(8)][dcb(16)][128][32] halfs    -> 1 MiB per plane
#define XTH_OFF 0ull
#define XTL_OFF 67108864ull
#define CBH_OFF 134217728ull
#define CBL_OFF 135266304ull
#define CSQ_OFF 136314880ull
#define WS_NEED (136314880ull + 4096ull)

#define GLOAD_LDS16(g, l) __builtin_amdgcn_global_load_lds( \
    (const __attribute__((address_space(1))) void*)(g),      \
    (__attribute__((address_space(3))) void*)(l), 16, 0, 0)

// ---------------------------------------------------------------------------
// csq[k] = sum_d cb[k][d]^2
// ---------------------------------------------------------------------------
__global__ void csq_kernel(const float* __restrict__ cb, float* __restrict__ csq) {
    int wave = threadIdx.x >> 6;
    int lane = threadIdx.x & 63;
    int row  = blockIdx.x * 4 + wave;
    const float* r = cb + (size_t)row * DD;
    float s = 0.f;
    #pragma unroll
    for (int i = 0; i < DD / 64; ++i) { float v = r[lane + i * 64]; s += v * v; }
    #pragma unroll
    for (int off = 32; off; off >>= 1) s += __shfl_down(s, off, 64);
    if (lane == 0) csq[row] = s;
}

// ---------------------------------------------------------------------------
// split x [B][D][T] fp32 -> tiled f16 planes [b][tb][dcb][128][32].
// ---------------------------------------------------------------------------
__global__ __launch_bounds__(256) void split_x_kernel(const float* __restrict__ x,
                                                      h16* __restrict__ xth,
                                                      h16* __restrict__ xtl) {
    __shared__ float xs[32][132];  // float4-stored rows, 16B-aligned stride
    const int tb = blockIdx.x, dcb = blockIdx.y, b = blockIdx.z;
    const int tid = threadIdx.x;
    const int t0 = tb * 128, d0 = dcb * 32;
    const float* xp = x + ((size_t)b * DD + d0) * TT + t0;
    #pragma unroll
    for (int j = 0; j < 4; ++j) {
        int i4 = tid + 256 * j;
        int dd = i4 >> 5, c4 = (i4 & 31) << 2;
        *(float4*)&xs[dd][c4] = *(const float4*)(xp + (size_t)dd * TT + c4);
    }
    __syncthreads();
    const int r = tid >> 1;              // t-local row of output
    const int ch = (tid & 1) * 16;       // d-half
    h16 hv[16], lv[16];
    #pragma unroll
    for (int i = 0; i < 16; ++i) {
        float v = xs[ch + i][r];
        h16 h = (h16)v;
        hv[i] = h;
        lv[i] = (h16)(v - (float)h);
    }
    size_t o = (((size_t)(b * 32 + tb) * 16) + dcb) * 4096 + (size_t)tid * 16;
    *(half8*)(xth + o)     = *(half8*)&hv[0];
    *(half8*)(xth + o + 8) = *(half8*)&hv[8];
    *(half8*)(xtl + o)     = *(half8*)&lv[0];
    *(half8*)(xtl + o + 8) = *(half8*)&lv[8];
}

// ---------------------------------------------------------------------------
// split cb [K][D] fp32 -> tiled f16 planes [kb][dcb][128][32]. No transpose.
// ---------------------------------------------------------------------------
__global__ __launch_bounds__(256) void split_cb_kernel(const float* __restrict__ cb,
                                                       h16* __restrict__ cbh,
                                                       h16* __restrict__ cbl) {
    const int kb = blockIdx.x >> 4, dcb = blockIdx.x & 15;
    const int tid = threadIdx.x;
    const float* cp = cb + ((size_t)kb * 128) * DD + dcb * 32;
    h16* oh = cbh + ((size_t)(kb * 16 + dcb)) * 4096;
    h16* ol = cbl + ((size_t)(kb * 16 + dcb)) * 4096;
    #pragma unroll
    for (int j = 0; j < 4; ++j) {
        int i4 = tid + 256 * j;
        int rr = i4 >> 3, c4 = (i4 & 7) << 2;
        float4 v = *(const float4*)(cp + (size_t)rr * DD + c4);
        float vv[4] = {v.x, v.y, v.z, v.w};
        h16 h[4], l[4];
        #pragma unroll
        for (int i = 0; i < 4; ++i) {
            h[i] = (h16)vv[i];
            l[i] = (h16)(vv[i] - (float)h[i]);
        }
        *(ushort4*)(oh + rr * 32 + c4) = *(ushort4*)h;
        *(ushort4*)(ol + rr * 32 + c4) = *(ushort4*)l;
    }
}

// ---------------------------------------------------------------------------
// fused f16x3-split MFMA GEMM + argmin + gather.
// score[t][k] = csq[k] - 2 * (xh.bh + xh.bl + xl.bh)
// v7: PHASE-INTERLEAVED schedule (guide T3+T4+T5) on the v5 geometry
// (128t x 256k tile, 8 waves 2x4, BK=32). 3-buffer LDS ring (148 KiB).
// Per D-step gi: 4 phases, each {ds_read next-cluster operands (2-6 b128)
// || 2 staging gloads -> barrier -> 12 MFMA setprio-wrapped}. Operands are
// always read one phase ahead (B[n] pairs ping-pong slotA/slotB; A-frags of
// gi+1 read in P2/P3 after counted vmcnt(4) -- never drained mid-loop).
// lgkmcnt(6) before P3's barrier closes the read-vs-restage race on the
// ring. Per-acc FP order AhBh -> AhBl -> AlBh per dcb, dcb/k ascending,
// fold at chunk ends: bit-identical to v5.
// ---------------------------------------------------------------------------
__global__ __launch_bounds__(512, 1) void mfma_argmin_kernel(
    const h16* __restrict__ xth, const h16* __restrict__ xtl,
    const h16* __restrict__ cbh, const h16* __restrict__ cbl,
    const float* __restrict__ csq, const float* __restrict__ cb,
    float* __restrict__ idx_f_out, float* __restrict__ out) {

    __shared__ h16 ash[3][4096];    // A high plane: [128][32]  (24 KiB)
    __shared__ h16 asl[3][4096];    // A low  plane             (24 KiB)
    __shared__ h16 bsh[3][8192];    // B high plane: [256][32]  (48 KiB)
    __shared__ h16 bsl[3][8192];    // B low  plane             (48 KiB)
    __shared__ float redv[4][128];
    __shared__ int   redi[4][128];

    const int tid = threadIdx.x;
    const int wid = tid >> 6, lane = tid & 63;
    const int wm = wid & 1;            // t-half of tile (0/1)
    const int wn = wid >> 1;           // k-quarter of 256-chunk (0..3)
    const int tb = blockIdx.x, b = blockIdx.y;
    const int t0 = tb * 128;
    const int c  = lane & 15;          // frag col
    const int q  = lane >> 4;          // frag quad

    const h16* aH = xth + ((size_t)(b * 32 + tb) * 16) * 4096;
    const h16* aL = xtl + ((size_t)(b * 32 + tb) * 16) * 4096;

    const int soff = tid * 8;          // halfs: 512 lanes x 16B = 8 KiB

    // fragment offsets within a plane (halfs)
    int arow[4];
    #pragma unroll
    for (int m = 0; m < 4; ++m) arow[m] = (wm * 64 + m * 16 + c) * 32 + q * 8;
    const int brow0 = (wn * 64 +  0 + c) * 32 + q * 8;
    const int brow1 = (wn * 64 + 16 + c) * 32 + q * 8;
    const int brow2 = (wn * 64 + 32 + c) * 32 + q * 8;
    const int brow3 = (wn * 64 + 48 + c) * 32 + q * 8;

#define STAGE_A(GI2, BS) do { const int dn_ = (GI2) & 15;                     \
        GLOAD_LDS16(aH + (size_t)dn_ * 4096 + soff, &ash[BS][soff]);          \
        GLOAD_LDS16(aL + (size_t)dn_ * 4096 + soff, &asl[BS][soff]); } while (0)
#define STAGE_BH(GI2, BS) do { const int dn_ = (GI2) & 15, kc_ = (GI2) >> 4;  \
        const size_t b0_ = ((size_t)(kc_ * 32 + dn_)) * 4096;                 \
        const size_t b1_ = ((size_t)(kc_ * 32 + 16 + dn_)) * 4096;            \
        GLOAD_LDS16(cbh + b0_ + soff, &bsh[BS][soff]);                        \
        GLOAD_LDS16(cbh + b1_ + soff, &bsh[BS][4096 + soff]); } while (0)
#define STAGE_BL(GI2, BS) do { const int dn_ = (GI2) & 15, kc_ = (GI2) >> 4;  \
        const size_t b0_ = ((size_t)(kc_ * 32 + dn_)) * 4096;                 \
        const size_t b1_ = ((size_t)(kc_ * 32 + 16 + dn_)) * 4096;            \
        GLOAD_LDS16(cbl + b0_ + soff, &bsl[BS][soff]);                        \
        GLOAD_LDS16(cbl + b1_ + soff, &bsl[BS][4096 + soff]); } while (0)

#define MF(a, bv, d) d = __builtin_amdgcn_mfma_f32_16x16x32_f16(a, bv, d, 0, 0, 0)
    // 12 MFMAs for column N: per-acc order AhBh -> AhBl -> AlBh
#define CLUSTER(N, BH, BL, ACh, ACl) do {                                     \
        MF(ACh[0], BH, acc[0][N]); MF(ACh[1], BH, acc[1][N]);                 \
        MF(ACh[2], BH, acc[2][N]); MF(ACh[3], BH, acc[3][N]);                 \
        MF(ACh[0], BL, acc[0][N]); MF(ACh[1], BL, acc[1][N]);                 \
        MF(ACh[2], BL, acc[2][N]); MF(ACh[3], BL, acc[3][N]);                 \
        MF(ACl[0], BH, acc[0][N]); MF(ACl[1], BH, acc[1][N]);                 \
        MF(ACl[2], BH, acc[2][N]); MF(ACl[3], BH, acc[3][N]); } while (0)

    float best[16];
    int   bidx[16];
    #pragma unroll
    for (int i = 0; i < 16; ++i) { best[i] = 3.4e38f; bidx[i] = 0; }

    float4v acc[4][4];
    #pragma unroll
    for (int m = 0; m < 4; ++m)
        #pragma unroll
        for (int n = 0; n < 4; ++n)
            acc[m][n] = (float4v){0.f, 0.f, 0.f, 0.f};

    int bc = 0, bn = 1, bs = 2;        // LDS ring: current / next / stage

    // prologue: stage gi=0 -> buf0, gi=1 -> buf1 (6 loads each)
    STAGE_A(0, 0); STAGE_BH(0, 0); STAGE_BL(0, 0);
    STAGE_A(1, 1); STAGE_BH(1, 1); STAGE_BL(1, 1);
    asm volatile("s_waitcnt vmcnt(6)" ::: "memory");   // gi0 resident
    __builtin_amdgcn_s_barrier();
    __builtin_amdgcn_sched_barrier(0);

    half8 A0h[4], A0l[4], A1h[4], A1l[4];
    half8 BhA, BlA, BhB, BlB;
    #pragma unroll
    for (int m = 0; m < 4; ++m) {
        A0h[m] = *(const half8*)(&ash[0][arow[m]]);
        A0l[m] = *(const half8*)(&asl[0][arow[m]]);
    }
    BhA = *(const half8*)(&bsh[0][brow0]);
    BlA = *(const half8*)(&bsl[0][brow0]);

    // phase body: SG = stage gi+2, VMMODE: 0=vmcnt(4), 1=vmcnt(0), 2=none,
    // RA = read-ahead gi+1 operands (A-next + B0-next)
#define GIBODY(GI, ACh, ACl, ANh, ANl, SG, VMMODE, RA) do {                   \
    /* ---- P0: cluster n=0 (slotA) ; read B1 -> slotB ; stage A ---- */      \
    BhB = *(const half8*)(&bsh[bc][brow1]);                                   \
    BlB = *(const half8*)(&bsl[bc][brow1]);                                   \
    if (SG) STAGE_A((GI) + 2, bs);                                            \
    __builtin_amdgcn_s_barrier();                                             \
    __builtin_amdgcn_s_setprio(1); CLUSTER(0, BhA, BlA, ACh, ACl);            \
    __builtin_amdgcn_s_setprio(0);                                            \
    /* ---- P1: cluster n=1 (slotB) ; read B2 -> slotA ; stage BH ---- */     \
    BhA = *(const half8*)(&bsh[bc][brow2]);                                   \
    BlA = *(const half8*)(&bsl[bc][brow2]);                                   \
    if (SG) STAGE_BH((GI) + 2, bs);                                           \
    __builtin_amdgcn_s_barrier();                                             \
    __builtin_amdgcn_s_setprio(1); CLUSTER(1, BhB, BlB, ACh, ACl);            \
    __builtin_amdgcn_s_setprio(0);                                            \
    /* ---- P2: vmcnt -> gi+1 resident ; stage BL ; read B3 + A-next ---- */  \
    if ((VMMODE) == 0)      asm volatile("s_waitcnt vmcnt(4)" ::: "memory");  \
    else if ((VMMODE) == 1) asm volatile("s_waitcnt vmcnt(0)" ::: "memory");  \
    __builtin_amdgcn_s_barrier();                                             \
    __builtin_amdgcn_sched_barrier(0);                                        \
    if (SG) STAGE_BL((GI) + 2, bs);                                           \
    BhB = *(const half8*)(&bsh[bc][brow3]);                                   \
    BlB = *(const half8*)(&bsl[bc][brow3]);                                   \
    if (RA) {                                                                 \
        ANh[0] = *(const half8*)(&ash[bn][arow[0]]);                          \
        ANh[1] = *(const half8*)(&ash[bn][arow[1]]);                          \
        ANl[0] = *(const half8*)(&asl[bn][arow[0]]);                          \
        ANl[1] = *(const half8*)(&asl[bn][arow[1]]);                          \
    }                                                                         \
    __builtin_amdgcn_s_setprio(1); CLUSTER(2, BhA, BlA, ACh, ACl);            \
    __builtin_amdgcn_s_setprio(0);                                            \
    /* ---- P3: read rest of A-next + B0-next ; close ring race ---- */       \
    if (RA) {                                                                 \
        ANh[2] = *(const half8*)(&ash[bn][arow[2]]);                          \
        ANh[3] = *(const half8*)(&ash[bn][arow[3]]);                          \
        ANl[2] = *(const half8*)(&asl[bn][arow[2]]);                          \
        ANl[3] = *(const half8*)(&asl[bn][arow[3]]);                          \
        BhA = *(const half8*)(&bsh[bn][brow0]);                               \
        BlA = *(const half8*)(&bsl[bn][brow0]);                               \
        asm volatile("s_waitcnt lgkmcnt(6)" ::: "memory");                    \
    }                                                                         \
    __builtin_amdgcn_s_barrier();                                             \
    __builtin_amdgcn_sched_barrier(0);                                        \
    __builtin_amdgcn_s_setprio(1); CLUSTER(3, BhB, BlB, ACh, ACl);            \
    __builtin_amdgcn_s_setprio(0);                                            \
    { int tr_ = bc; bc = bn; bn = bs; bs = tr_; }                             \
} while (0)

#define FOLD(KCI) do {                                                        \
        _Pragma("unroll")                                                     \
        for (int n_ = 0; n_ < 4; ++n_) {                                      \
            int kg_ = (KCI) * 256 + wn * 64 + n_ * 16 + c;                    \
            float cq_ = csq[kg_];                                             \
            _Pragma("unroll")                                                 \
            for (int m_ = 0; m_ < 4; ++m_)                                    \
                _Pragma("unroll")                                             \
                for (int r_ = 0; r_ < 4; ++r_) {                              \
                    float s_ = fmaf(-2.0f, acc[m_][n_][r_], cq_);             \
                    int slot_ = m_ * 4 + r_;                                  \
                    if (s_ < best[slot_]) { best[slot_] = s_; bidx[slot_] = kg_; } \
                }                                                             \
        }                                                                     \
        _Pragma("unroll")                                                     \
        for (int m_ = 0; m_ < 4; ++m_)                                        \
            _Pragma("unroll")                                                 \
            for (int n_ = 0; n_ < 4; ++n_)                                    \
                acc[m_][n_] = (float4v){0.f, 0.f, 0.f, 0.f};                  \
    } while (0)

    for (int gp = 0; gp < 31; ++gp) {
        const int gi = gp * 2;
        GIBODY(gi,     A0h, A0l, A1h, A1l, 1, 0, 1);
        GIBODY(gi + 1, A1h, A1l, A0h, A0l, 1, 0, 1);
        if ((gp & 7) == 7) FOLD(gp >> 3);     // after gi 15 / 31 / 47
    }
    // epilogue: gi=62 (no staging, drain vmcnt), gi=63 (no read-ahead)
    GIBODY(62, A0h, A0l, A1h, A1l, 0, 1, 1);
    GIBODY(63, A1h, A1l, A0h, A0l, 0, 2, 0);
    FOLD(3);

#undef GIBODY
#undef FOLD
#undef CLUSTER
#undef MF
#undef STAGE_A
#undef STAGE_BH
#undef STAGE_BL

    // reduce over the 16 frag columns (lanes sharing a t)
    #pragma unroll
    for (int slot = 0; slot < 16; ++slot) {
        float v = best[slot]; int i = bidx[slot];
        #pragma unroll
        for (int d = 1; d < 16; d <<= 1) {
            float pv = __shfl_xor(v, d);
            int   pi = __shfl_xor(i, d);
            if (pv < v || (pv == v && pi < i)) { v = pv; i = pi; }
        }
        if (c == 0) {
            int m = slot >> 2, r = slot & 3;
            int tl = wm * 64 + m * 16 + q * 4 + r;
            redv[wn][tl] = v; redi[wn][tl] = i;
        }
    }
    __syncthreads();
    if (tid < 128) {
        float v0 = redv[0][tid]; int i0 = redi[0][tid];
        #pragma unroll
        for (int gi = 1; gi < 4; ++gi) {
            float v1 = redv[gi][tid]; int i1 = redi[gi][tid];
            if (v1 < v0 || (v1 == v0 && i1 < i0)) { v0 = v1; i0 = i1; }
        }
        idx_f_out[(size_t)b * TT + t0 + tid] = (float)i0;
        redi[0][tid] = i0;                 // broadcast final index
    }
    __syncthreads();

    // fused gather: out[b][d][t0+tl] = cb[k][d]; 512 threads -> 128 d each
    const int tl = tid & 127, dg = tid >> 7;
    const int k = redi[0][tl];
    const float* row = cb + (size_t)k * DD + dg * 128;
    float* ob = out + ((size_t)b * DD + dg * 128) * TT + t0 + tl;
    #pragma unroll 4
    for (int i = 0; i < 32; ++i) {
        float4 v = *(const float4*)(row + i * 4);
        ob[(size_t)(i * 4 + 0) * TT] = v.x;
        ob[(size_t)(i * 4 + 1) * TT] = v.y;
        ob[(size_t)(i * 4 + 2) * TT] = v.z;
        ob[(size_t)(i * 4 + 3) * TT] = v.w;
    }
}

// ---------------------------------------------------------------------------
// fallback fp32 path + standalone gather (used only if ws too small)
// ---------------------------------------------------------------------------
__global__ void gather_kernel(const float* __restrict__ cb,
                              const float* __restrict__ idx_f,
                              float* __restrict__ out) {
    int b  = blockIdx.y;
    int t  = blockIdx.x * 256 + threadIdx.x;
    int d0 = blockIdx.z * (DD / 4);
    int k  = (int)idx_f[(size_t)b * TT + t];
    const float* row = cb + (size_t)k * DD;
    float* ob = out + (size_t)b * DD * TT + t;
    #pragma unroll 8
    for (int d = d0; d < d0 + DD / 4; ++d)
        ob[(size_t)d * TT] = row[d];
}

__global__ __launch_bounds__(256) void argmin_fp32_kernel(
    const float* __restrict__ x, const float* __restrict__ cb,
    const float* __restrict__ csq, float* __restrict__ idx_f_out) {

    __shared__ float xs[32][128];
    __shared__ float cs[32][132];

    const int tid = threadIdx.x;
    const int b = blockIdx.y;
    const int t_blk = blockIdx.x * 128;
    const int tq = tid & 15, kq = tid >> 4;
    const int t0 = tq * 8, k0 = kq * 8;
    const float* xb = x + (size_t)b * DD * TT;

    float best[8]; int bidx[8];
    #pragma unroll
    for (int i = 0; i < 8; ++i) { best[i] = 3.4e38f; bidx[i] = 0; }

    for (int kc = 0; kc < KK; kc += 128) {
        float acc[8][8];
        #pragma unroll
        for (int i = 0; i < 8; ++i)
            #pragma unroll
            for (int j = 0; j < 8; ++j) acc[i][j] = 0.f;
        for (int dc = 0; dc < DD; dc += 32) {
            __syncthreads();
            #pragma unroll
            for (int j = 0; j < 4; ++j) {
                int i4 = tid + 256 * j;
                int dd = i4 >> 5, tp = (i4 & 31) << 2;
                *(float4*)&xs[dd][tp] =
                    *(const float4*)(xb + (size_t)(dc + dd) * TT + t_blk + tp);
            }
            #pragma unroll
            for (int j = 0; j < 4; ++j) {
                int i4 = tid + 256 * j;
                int kk = i4 >> 3, dq = (i4 & 7) << 2;
                float4 v = *(const float4*)(cb + (size_t)(kc + kk) * DD + dc + dq);
                cs[dq + 0][kk] = v.x; cs[dq + 1][kk] = v.y;
                cs[dq + 2][kk] = v.z; cs[dq + 3][kk] = v.w;
            }
            __syncthreads();
            #pragma unroll 8
            for (int dd = 0; dd < 32; ++dd) {
                float a[8], bv[8];
                *(float4*)&a[0]  = *(const float4*)&xs[dd][t0];
                *(float4*)&a[4]  = *(const float4*)&xs[dd][t0 + 4];
                *(float4*)&bv[0] = *(const float4*)&cs[dd][k0];
                *(float4*)&bv[4] = *(const float4*)&cs[dd][k0 + 4];
                #pragma unroll
                for (int i = 0; i < 8; ++i)
                    #pragma unroll
                    for (int j = 0; j < 8; ++j)
                        acc[i][j] = fmaf(a[i], bv[j], acc[i][j]);
            }
        }
        #pragma unroll
        for (int j = 0; j < 8; ++j) {
            int kg = kc + k0 + j;
            float cq = csq[kg];
            #pragma unroll
            for (int i = 0; i < 8; ++i) {
                float s = cq - 2.0f * acc[i][j];
                if (s < best[i]) { best[i] = s; bidx[i] = kg; }
            }
        }
    }
    __syncthreads();
    float* rbest = &xs[0][0];
    int*   ridx  = (int*)&cs[0][0];
    #pragma unroll
    for (int i = 0; i < 8; ++i) {
        rbest[kq * 128 + t0 + i] = best[i];
        ridx [kq * 128 + t0 + i] = bidx[i];
    }
    __syncthreads();
    if (tid < 128) {
        float bv = rbest[tid]; int bi = ridx[tid];
        #pragma unroll
        for (int g = 1; g < 16; ++g) {
            float v = rbest[g * 128 + tid]; int ii = ridx[g * 128 + tid];
            if (v < bv || (v == bv && ii < bi)) { bv = v; bi = ii; }
        }
        idx_f_out[(size_t)b * TT + t_blk + tid] = (float)bi;
    }
}

extern "C" void kernel_launch(void* const* d_in, const int* in_sizes, int n_in,
                              void* d_out, int out_size, void* d_ws, size_t ws_size,
                              hipStream_t stream) {
    const float* x  = (const float*)d_in[0];
    const float* cb = (const float*)d_in[1];
    float* out   = (float*)d_out;
    float* idx_f = out + (size_t)BB * DD * TT;

    if (ws_size >= WS_NEED) {
        h16* xth = (h16*)((char*)d_ws + XTH_OFF);
        h16* xtl = (h16*)((char*)d_ws + XTL_OFF);
        h16* cbh = (h16*)((char*)d_ws + CBH_OFF);
        h16* cbl = (h16*)((char*)d_ws + CBL_OFF);
        float* csq = (float*)((char*)d_ws + CSQ_OFF);

        csq_kernel<<<KK / 4, 256, 0, stream>>>(cb, csq);
        split_cb_kernel<<<128, 256, 0, stream>>>(cb, cbh, cbl);
        split_x_kernel<<<dim3(TT / 128, DD / 32, BB), 256, 0, stream>>>(x, xth, xtl);
        mfma_argmin_kernel<<<dim3(TT / 128, BB), 512, 0, stream>>>(
            xth, xtl, cbh, cbl, csq, cb, idx_f, out);
    } else {
        float* csq = (float*)d_ws;
        csq_kernel<<<KK / 4, 256, 0, stream>>>(cb, csq);
        argmin_fp32_kernel<<<dim3(TT / 128, BB), 256, 0, stream>>>(x, cb, csq, idx_f);
        gather_kernel<<<dim3(TT / 256, BB, 4), 256, 0, stream>>>(cb, idx_f, out);
    }
}

// Round 7
// 477.172 us; speedup vs baseline: 1.0956x; 1.0157x over previous
//
#include <hip/hip_runtime.h>

#define BB 16
#define DD 512
#define TT 4096
#define KK 1024

typedef _Float16 h16;
typedef __attribute__((ext_vector_type(8))) _Float16 half8;
typedef __attribute__((ext_vector_type(4))) float float4v;

// ---- ws layout (main path), bytes ----
// xth/xtl tiled: [b][tb(32)][dcb(16)][128][32] halfs -> 64 MiB per plane
// cbh/cbl tiled: [kb(8)][dcb(16)][128][32] halfs    -> 1 MiB per plane
#define XTH_OFF 0ull
#define XTL_OFF 67108864ull
#define CBH_OFF 134217728ull
#define CBL_OFF 135266304ull
#define CSQ_OFF 136314880ull
#define WS_NEED (136314880ull + 4096ull)

#define GLOAD_LDS16(g, l) __builtin_amdgcn_global_load_lds( \
    (const __attribute__((address_space(1))) void*)(g),      \
    (__attribute__((address_space(3))) void*)(l), 16, 0, 0)

// ---------------------------------------------------------------------------
// csq[k] = sum_d cb[k][d]^2
// ---------------------------------------------------------------------------
__global__ void csq_kernel(const float* __restrict__ cb, float* __restrict__ csq) {
    int wave = threadIdx.x >> 6;
    int lane = threadIdx.x & 63;
    int row  = blockIdx.x * 4 + wave;
    const float* r = cb + (size_t)row * DD;
    float s = 0.f;
    #pragma unroll
    for (int i = 0; i < DD / 64; ++i) { float v = r[lane + i * 64]; s += v * v; }
    #pragma unroll
    for (int off = 32; off; off >>= 1) s += __shfl_down(s, off, 64);
    if (lane == 0) csq[row] = s;
}

// ---------------------------------------------------------------------------
// split x [B][D][T] fp32 -> tiled f16 planes [b][tb][dcb][128][32].
// ---------------------------------------------------------------------------
__global__ __launch_bounds__(256) void split_x_kernel(const float* __restrict__ x,
                                                      h16* __restrict__ xth,
                                                      h16* __restrict__ xtl) {
    __shared__ float xs[32][132];  // float4-stored rows, 16B-aligned stride
    const int tb = blockIdx.x, dcb = blockIdx.y, b = blockIdx.z;
    const int tid = threadIdx.x;
    const int t0 = tb * 128, d0 = dcb * 32;
    const float* xp = x + ((size_t)b * DD + d0) * TT + t0;
    #pragma unroll
    for (int j = 0; j < 4; ++j) {
        int i4 = tid + 256 * j;
        int dd = i4 >> 5, c4 = (i4 & 31) << 2;
        *(float4*)&xs[dd][c4] = *(const float4*)(xp + (size_t)dd * TT + c4);
    }
    __syncthreads();
    const int r = tid >> 1;              // t-local row of output
    const int ch = (tid & 1) * 16;       // d-half
    h16 hv[16], lv[16];
    #pragma unroll
    for (int i = 0; i < 16; ++i) {
        float v = xs[ch + i][r];
        h16 h = (h16)v;
        hv[i] = h;
        lv[i] = (h16)(v - (float)h);
    }
    size_t o = (((size_t)(b * 32 + tb) * 16) + dcb) * 4096 + (size_t)tid * 16;
    *(half8*)(xth + o)     = *(half8*)&hv[0];
    *(half8*)(xth + o + 8) = *(half8*)&hv[8];
    *(half8*)(xtl + o)     = *(half8*)&lv[0];
    *(half8*)(xtl + o + 8) = *(half8*)&lv[8];
}

// ---------------------------------------------------------------------------
// split cb [K][D] fp32 -> tiled f16 planes [kb][dcb][128][32]. No transpose.
// ---------------------------------------------------------------------------
__global__ __launch_bounds__(256) void split_cb_kernel(const float* __restrict__ cb,
                                                       h16* __restrict__ cbh,
                                                       h16* __restrict__ cbl) {
    const int kb = blockIdx.x >> 4, dcb = blockIdx.x & 15;
    const int tid = threadIdx.x;
    const float* cp = cb + ((size_t)kb * 128) * DD + dcb * 32;
    h16* oh = cbh + ((size_t)(kb * 16 + dcb)) * 4096;
    h16* ol = cbl + ((size_t)(kb * 16 + dcb)) * 4096;
    #pragma unroll
    for (int j = 0; j < 4; ++j) {
        int i4 = tid + 256 * j;
        int rr = i4 >> 3, c4 = (i4 & 7) << 2;
        float4 v = *(const float4*)(cp + (size_t)rr * DD + c4);
        float vv[4] = {v.x, v.y, v.z, v.w};
        h16 h[4], l[4];
        #pragma unroll
        for (int i = 0; i < 4; ++i) {
            h[i] = (h16)vv[i];
            l[i] = (h16)(vv[i] - (float)h[i]);
        }
        *(ushort4*)(oh + rr * 32 + c4) = *(ushort4*)h;
        *(ushort4*)(ol + rr * 32 + c4) = *(ushort4*)l;
    }
}

// ---------------------------------------------------------------------------
// fused f16x3-split MFMA GEMM + argmin + gather.
// score[t][k] = csq[k] - 2 * (xh.bh + xh.bl + xl.bh)
// v8 = v7 structure + T2 XOR-SWIZZLE on the LDS tiles.
// ROOT CAUSE (v1..v7 all ~270us): [128][32]-half tiles have 64B row stride
// -> every frag ds_read_b128 is an 8-way bank conflict (~32cy each);
// 16384 reads/CU x 32cy = 218us ~ 81% of the wall. LDS pipe saturated ->
// no schedule could help. Evidence: v6 (no-LDS) had BANK_CONFLICT=0; all
// LDS variants had identical 1.678e7 (same read count).
// FIX: slot' = slot ^ ((row>>1)&3) within each 64B row.
//  - store side: global_load_lds writes LDS linearly, so the per-lane
//    GLOBAL source address carries the inverse permutation (rule #21):
//    gsoff = (tid>>2)*32 + ((tid&3)^((tid>>3)&3))*8 halfs.
//  - read side: qo = (q ^ ((c>>1)&3))*8  (row bits 1,2 == c bits 1,2).
// LDS(r,s)=global(r,s^sw(r)); read at (r,q^sw(r)) -> global(r,q): same
// values into same MFMAs -> bit-identical, absmax 0.0.
// 8-way -> 2-way (free, m136). Schedule/FP order unchanged from v7.
// ---------------------------------------------------------------------------
__global__ __launch_bounds__(512, 1) void mfma_argmin_kernel(
    const h16* __restrict__ xth, const h16* __restrict__ xtl,
    const h16* __restrict__ cbh, const h16* __restrict__ cbl,
    const float* __restrict__ csq, const float* __restrict__ cb,
    float* __restrict__ idx_f_out, float* __restrict__ out) {

    __shared__ h16 ash[3][4096];    // A high plane: [128][32]  (24 KiB)
    __shared__ h16 asl[3][4096];    // A low  plane             (24 KiB)
    __shared__ h16 bsh[3][8192];    // B high plane: [256][32]  (48 KiB)
    __shared__ h16 bsl[3][8192];    // B low  plane             (48 KiB)
    __shared__ float redv[4][128];
    __shared__ int   redi[4][128];

    const int tid = threadIdx.x;
    const int wid = tid >> 6, lane = tid & 63;
    const int wm = wid & 1;            // t-half of tile (0/1)
    const int wn = wid >> 1;           // k-quarter of 256-chunk (0..3)
    const int tb = blockIdx.x, b = blockIdx.y;
    const int t0 = tb * 128;
    const int c  = lane & 15;          // frag col
    const int q  = lane >> 4;          // frag quad

    const h16* aH = xth + ((size_t)(b * 32 + tb) * 16) * 4096;
    const h16* aL = xtl + ((size_t)(b * 32 + tb) * 16) * 4096;

    const int soff  = tid * 8;         // LDS dest (linear), halfs
    // inverse-swizzled global source offset (halfs): row=tid>>2, slot=tid&3
    const int gsoff = ((tid >> 2) * 32) + ((((tid & 3) ^ ((tid >> 3) & 3))) * 8);

    // fragment offsets within a plane (halfs), swizzled slot
    const int qo = (q ^ ((c >> 1) & 3)) * 8;
    int arow[4];
    #pragma unroll
    for (int m = 0; m < 4; ++m) arow[m] = (wm * 64 + m * 16 + c) * 32 + qo;
    const int brow0 = (wn * 64 +  0 + c) * 32 + qo;
    const int brow1 = (wn * 64 + 16 + c) * 32 + qo;
    const int brow2 = (wn * 64 + 32 + c) * 32 + qo;
    const int brow3 = (wn * 64 + 48 + c) * 32 + qo;

#define STAGE_A(GI2, BS) do { const int dn_ = (GI2) & 15;                     \
        GLOAD_LDS16(aH + (size_t)dn_ * 4096 + gsoff, &ash[BS][soff]);         \
        GLOAD_LDS16(aL + (size_t)dn_ * 4096 + gsoff, &asl[BS][soff]); } while (0)
#define STAGE_BH(GI2, BS) do { const int dn_ = (GI2) & 15, kc_ = (GI2) >> 4;  \
        const size_t b0_ = ((size_t)(kc_ * 32 + dn_)) * 4096;                 \
        const size_t b1_ = ((size_t)(kc_ * 32 + 16 + dn_)) * 4096;            \
        GLOAD_LDS16(cbh + b0_ + gsoff, &bsh[BS][soff]);                       \
        GLOAD_LDS16(cbh + b1_ + gsoff, &bsh[BS][4096 + soff]); } while (0)
#define STAGE_BL(GI2, BS) do { const int dn_ = (GI2) & 15, kc_ = (GI2) >> 4;  \
        const size_t b0_ = ((size_t)(kc_ * 32 + dn_)) * 4096;                 \
        const size_t b1_ = ((size_t)(kc_ * 32 + 16 + dn_)) * 4096;            \
        GLOAD_LDS16(cbl + b0_ + gsoff, &bsl[BS][soff]);                       \
        GLOAD_LDS16(cbl + b1_ + gsoff, &bsl[BS][4096 + soff]); } while (0)

#define MF(a, bv, d) d = __builtin_amdgcn_mfma_f32_16x16x32_f16(a, bv, d, 0, 0, 0)
    // 12 MFMAs for column N: per-acc order AhBh -> AhBl -> AlBh
#define CLUSTER(N, BH, BL, ACh, ACl) do {                                     \
        MF(ACh[0], BH, acc[0][N]); MF(ACh[1], BH, acc[1][N]);                 \
        MF(ACh[2], BH, acc[2][N]); MF(ACh[3], BH, acc[3][N]);                 \
        MF(ACh[0], BL, acc[0][N]); MF(ACh[1], BL, acc[1][N]);                 \
        MF(ACh[2], BL, acc[2][N]); MF(ACh[3], BL, acc[3][N]);                 \
        MF(ACl[0], BH, acc[0][N]); MF(ACl[1], BH, acc[1][N]);                 \
        MF(ACl[2], BH, acc[2][N]); MF(ACl[3], BH, acc[3][N]); } while (0)

    float best[16];
    int   bidx[16];
    #pragma unroll
    for (int i = 0; i < 16; ++i) { best[i] = 3.4e38f; bidx[i] = 0; }

    float4v acc[4][4];
    #pragma unroll
    for (int m = 0; m < 4; ++m)
        #pragma unroll
        for (int n = 0; n < 4; ++n)
            acc[m][n] = (float4v){0.f, 0.f, 0.f, 0.f};

    int bc = 0, bn = 1, bs = 2;        // LDS ring: current / next / stage

    // prologue: stage gi=0 -> buf0, gi=1 -> buf1 (6 loads each)
    STAGE_A(0, 0); STAGE_BH(0, 0); STAGE_BL(0, 0);
    STAGE_A(1, 1); STAGE_BH(1, 1); STAGE_BL(1, 1);
    asm volatile("s_waitcnt vmcnt(6)" ::: "memory");   // gi0 resident
    __builtin_amdgcn_s_barrier();
    __builtin_amdgcn_sched_barrier(0);

    half8 A0h[4], A0l[4], A1h[4], A1l[4];
    half8 BhA, BlA, BhB, BlB;
    #pragma unroll
    for (int m = 0; m < 4; ++m) {
        A0h[m] = *(const half8*)(&ash[0][arow[m]]);
        A0l[m] = *(const half8*)(&asl[0][arow[m]]);
    }
    BhA = *(const half8*)(&bsh[0][brow0]);
    BlA = *(const half8*)(&bsl[0][brow0]);

    // phase body: SG = stage gi+2, VMMODE: 0=vmcnt(4), 1=vmcnt(0), 2=none,
    // RA = read-ahead gi+1 operands (A-next + B0-next)
#define GIBODY(GI, ACh, ACl, ANh, ANl, SG, VMMODE, RA) do {                   \
    /* ---- P0: cluster n=0 (slotA) ; read B1 -> slotB ; stage A ---- */      \
    BhB = *(const half8*)(&bsh[bc][brow1]);                                   \
    BlB = *(const half8*)(&bsl[bc][brow1]);                                   \
    if (SG) STAGE_A((GI) + 2, bs);                                            \
    __builtin_amdgcn_s_barrier();                                             \
    __builtin_amdgcn_s_setprio(1); CLUSTER(0, BhA, BlA, ACh, ACl);            \
    __builtin_amdgcn_s_setprio(0);                                            \
    /* ---- P1: cluster n=1 (slotB) ; read B2 -> slotA ; stage BH ---- */     \
    BhA = *(const half8*)(&bsh[bc][brow2]);                                   \
    BlA = *(const half8*)(&bsl[bc][brow2]);                                   \
    if (SG) STAGE_BH((GI) + 2, bs);                                           \
    __builtin_amdgcn_s_barrier();                                             \
    __builtin_amdgcn_s_setprio(1); CLUSTER(1, BhB, BlB, ACh, ACl);            \
    __builtin_amdgcn_s_setprio(0);                                            \
    /* ---- P2: vmcnt -> gi+1 resident ; stage BL ; read B3 + A-next ---- */  \
    if ((VMMODE) == 0)      asm volatile("s_waitcnt vmcnt(4)" ::: "memory");  \
    else if ((VMMODE) == 1) asm volatile("s_waitcnt vmcnt(0)" ::: "memory");  \
    __builtin_amdgcn_s_barrier();                                             \
    __builtin_amdgcn_sched_barrier(0);                                        \
    if (SG) STAGE_BL((GI) + 2, bs);                                           \
    BhB = *(const half8*)(&bsh[bc][brow3]);                                   \
    BlB = *(const half8*)(&bsl[bc][brow3]);                                   \
    if (RA) {                                                                 \
        ANh[0] = *(const half8*)(&ash[bn][arow[0]]);                          \
        ANh[1] = *(const half8*)(&ash[bn][arow[1]]);                          \
        ANl[0] = *(const half8*)(&asl[bn][arow[0]]);                          \
        ANl[1] = *(const half8*)(&asl[bn][arow[1]]);                          \
    }                                                                         \
    __builtin_amdgcn_s_setprio(1); CLUSTER(2, BhA, BlA, ACh, ACl);            \
    __builtin_amdgcn_s_setprio(0);                                            \
    /* ---- P3: read rest of A-next + B0-next ; close ring race ---- */       \
    if (RA) {                                                                 \
        ANh[2] = *(const half8*)(&ash[bn][arow[2]]);                          \
        ANh[3] = *(const half8*)(&ash[bn][arow[3]]);                          \
        ANl[2] = *(const half8*)(&asl[bn][arow[2]]);                          \
        ANl[3] = *(const half8*)(&asl[bn][arow[3]]);                          \
        BhA = *(const half8*)(&bsh[bn][brow0]);                               \
        BlA = *(const half8*)(&bsl[bn][brow0]);                               \
        asm volatile("s_waitcnt lgkmcnt(6)" ::: "memory");                    \
    }                                                                         \
    __builtin_amdgcn_s_barrier();                                             \
    __builtin_amdgcn_sched_barrier(0);                                        \
    __builtin_amdgcn_s_setprio(1); CLUSTER(3, BhB, BlB, ACh, ACl);            \
    __builtin_amdgcn_s_setprio(0);                                            \
    { int tr_ = bc; bc = bn; bn = bs; bs = tr_; }                             \
} while (0)

#define FOLD(KCI) do {                                                        \
        _Pragma("unroll")                                                     \
        for (int n_ = 0; n_ < 4; ++n_) {                                      \
            int kg_ = (KCI) * 256 + wn * 64 + n_ * 16 + c;                    \
            float cq_ = csq[kg_];                                             \
            _Pragma("unroll")                                                 \
            for (int m_ = 0; m_ < 4; ++m_)                                    \
                _Pragma("unroll")                                             \
                for (int r_ = 0; r_ < 4; ++r_) {                              \
                    float s_ = fmaf(-2.0f, acc[m_][n_][r_], cq_);             \
                    int slot_ = m_ * 4 + r_;                                  \
                    if (s_ < best[slot_]) { best[slot_] = s_; bidx[slot_] = kg_; } \
                }                                                             \
        }                                                                     \
        _Pragma("unroll")                                                     \
        for (int m_ = 0; m_ < 4; ++m_)                                        \
            _Pragma("unroll")                                                 \
            for (int n_ = 0; n_ < 4; ++n_)                                    \
                acc[m_][n_] = (float4v){0.f, 0.f, 0.f, 0.f};                  \
    } while (0)

    for (int gp = 0; gp < 31; ++gp) {
        const int gi = gp * 2;
        GIBODY(gi,     A0h, A0l, A1h, A1l, 1, 0, 1);
        GIBODY(gi + 1, A1h, A1l, A0h, A0l, 1, 0, 1);
        if ((gp & 7) == 7) FOLD(gp >> 3);     // after gi 15 / 31 / 47
    }
    // epilogue: gi=62 (no staging, drain vmcnt), gi=63 (no read-ahead)
    GIBODY(62, A0h, A0l, A1h, A1l, 0, 1, 1);
    GIBODY(63, A1h, A1l, A0h, A0l, 0, 2, 0);
    FOLD(3);

#undef GIBODY
#undef FOLD
#undef CLUSTER
#undef MF
#undef STAGE_A
#undef STAGE_BH
#undef STAGE_BL

    // reduce over the 16 frag columns (lanes sharing a t)
    #pragma unroll
    for (int slot = 0; slot < 16; ++slot) {
        float v = best[slot]; int i = bidx[slot];
        #pragma unroll
        for (int d = 1; d < 16; d <<= 1) {
            float pv = __shfl_xor(v, d);
            int   pi = __shfl_xor(i, d);
            if (pv < v || (pv == v && pi < i)) { v = pv; i = pi; }
        }
        if (c == 0) {
            int m = slot >> 2, r = slot & 3;
            int tl = wm * 64 + m * 16 + q * 4 + r;
            redv[wn][tl] = v; redi[wn][tl] = i;
        }
    }
    __syncthreads();
    if (tid < 128) {
        float v0 = redv[0][tid]; int i0 = redi[0][tid];
        #pragma unroll
        for (int gi = 1; gi < 4; ++gi) {
            float v1 = redv[gi][tid]; int i1 = redi[gi][tid];
            if (v1 < v0 || (v1 == v0 && i1 < i0)) { v0 = v1; i0 = i1; }
        }
        idx_f_out[(size_t)b * TT + t0 + tid] = (float)i0;
        redi[0][tid] = i0;                 // broadcast final index
    }
    __syncthreads();

    // fused gather: out[b][d][t0+tl] = cb[k][d]; 512 threads -> 128 d each
    const int tl = tid & 127, dg = tid >> 7;
    const int k = redi[0][tl];
    const float* row = cb + (size_t)k * DD + dg * 128;
    float* ob = out + ((size_t)b * DD + dg * 128) * TT + t0 + tl;
    #pragma unroll 4
    for (int i = 0; i < 32; ++i) {
        float4 v = *(const float4*)(row + i * 4);
        ob[(size_t)(i * 4 + 0) * TT] = v.x;
        ob[(size_t)(i * 4 + 1) * TT] = v.y;
        ob[(size_t)(i * 4 + 2) * TT] = v.z;
        ob[(size_t)(i * 4 + 3) * TT] = v.w;
    }
}

// ---------------------------------------------------------------------------
// fallback fp32 path + standalone gather (used only if ws too small)
// ---------------------------------------------------------------------------
__global__ void gather_kernel(const float* __restrict__ cb,
                              const float* __restrict__ idx_f,
                              float* __restrict__ out) {
    int b  = blockIdx.y;
    int t  = blockIdx.x * 256 + threadIdx.x;
    int d0 = blockIdx.z * (DD / 4);
    int k  = (int)idx_f[(size_t)b * TT + t];
    const float* row = cb + (size_t)k * DD;
    float* ob = out + (size_t)b * DD * TT + t;
    #pragma unroll 8
    for (int d = d0; d < d0 + DD / 4; ++d)
        ob[(size_t)d * TT] = row[d];
}

__global__ __launch_bounds__(256) void argmin_fp32_kernel(
    const float* __restrict__ x, const float* __restrict__ cb,
    const float* __restrict__ csq, float* __restrict__ idx_f_out) {

    __shared__ float xs[32][128];
    __shared__ float cs[32][132];

    const int tid = threadIdx.x;
    const int b = blockIdx.y;
    const int t_blk = blockIdx.x * 128;
    const int tq = tid & 15, kq = tid >> 4;
    const int t0 = tq * 8, k0 = kq * 8;
    const float* xb = x + (size_t)b * DD * TT;

    float best[8]; int bidx[8];
    #pragma unroll
    for (int i = 0; i < 8; ++i) { best[i] = 3.4e38f; bidx[i] = 0; }

    for (int kc = 0; kc < KK; kc += 128) {
        float acc[8][8];
        #pragma unroll
        for (int i = 0; i < 8; ++i)
            #pragma unroll
            for (int j = 0; j < 8; ++j) acc[i][j] = 0.f;
        for (int dc = 0; dc < DD; dc += 32) {
            __syncthreads();
            #pragma unroll
            for (int j = 0; j < 4; ++j) {
                int i4 = tid + 256 * j;
                int dd = i4 >> 5, tp = (i4 & 31) << 2;
                *(float4*)&xs[dd][tp] =
                    *(const float4*)(xb + (size_t)(dc + dd) * TT + t_blk + tp);
            }
            #pragma unroll
            for (int j = 0; j < 4; ++j) {
                int i4 = tid + 256 * j;
                int kk = i4 >> 3, dq = (i4 & 7) << 2;
                float4 v = *(const float4*)(cb + (size_t)(kc + kk) * DD + dc + dq);
                cs[dq + 0][kk] = v.x; cs[dq + 1][kk] = v.y;
                cs[dq + 2][kk] = v.z; cs[dq + 3][kk] = v.w;
            }
            __syncthreads();
            #pragma unroll 8
            for (int dd = 0; dd < 32; ++dd) {
                float a[8], bv[8];
                *(float4*)&a[0]  = *(const float4*)&xs[dd][t0];
                *(float4*)&a[4]  = *(const float4*)&xs[dd][t0 + 4];
                *(float4*)&bv[0] = *(const float4*)&cs[dd][k0];
                *(float4*)&bv[4] = *(const float4*)&cs[dd][k0 + 4];
                #pragma unroll
                for (int i = 0; i < 8; ++i)
                    #pragma unroll
                    for (int j = 0; j < 8; ++j)
                        acc[i][j] = fmaf(a[i], bv[j], acc[i][j]);
            }
        }
        #pragma unroll
        for (int j = 0; j < 8; ++j) {
            int kg = kc + k0 + j;
            float cq = csq[kg];
            #pragma unroll
            for (int i = 0; i < 8; ++i) {
                float s = cq - 2.0f * acc[i][j];
                if (s < best[i]) { best[i] = s; bidx[i] = kg; }
            }
        }
    }
    __syncthreads();
    float* rbest = &xs[0][0];
    int*   ridx  = (int*)&cs[0][0];
    #pragma unroll
    for (int i = 0; i < 8; ++i) {
        rbest[kq * 128 + t0 + i] = best[i];
        ridx [kq * 128 + t0 + i] = bidx[i];
    }
    __syncthreads();
    if (tid < 128) {
        float bv = rbest[tid]; int bi = ridx[tid];
        #pragma unroll
        for (int g = 1; g < 16; ++g) {
            float v = rbest[g * 128 + tid]; int ii = ridx[g * 128 + tid];
            if (v < bv || (v == bv && ii < bi)) { bv = v; bi = ii; }
        }
        idx_f_out[(size_t)b * TT + t_blk + tid] = (float)bi;
    }
}

extern "C" void kernel_launch(void* const* d_in, const int* in_sizes, int n_in,
                              void* d_out, int out_size, void* d_ws, size_t ws_size,
                              hipStream_t stream) {
    const float* x  = (const float*)d_in[0];
    const float* cb = (const float*)d_in[1];
    float* out   = (float*)d_out;
    float* idx_f = out + (size_t)BB * DD * TT;

    if (ws_size >= WS_NEED) {
        h16* xth = (h16*)((char*)d_ws + XTH_OFF);
        h16* xtl = (h16*)((char*)d_ws + XTL_OFF);
        h16* cbh = (h16*)((char*)d_ws + CBH_OFF);
        h16* cbl = (h16*)((char*)d_ws + CBL_OFF);
        float* csq = (float*)((char*)d_ws + CSQ_OFF);

        csq_kernel<<<KK / 4, 256, 0, stream>>>(cb, csq);
        split_cb_kernel<<<128, 256, 0, stream>>>(cb, cbh, cbl);
        split_x_kernel<<<dim3(TT / 128, DD / 32, BB), 256, 0, stream>>>(x, xth, xtl);
        mfma_argmin_kernel<<<dim3(TT / 128, BB), 512, 0, stream>>>(
            xth, xtl, cbh, cbl, csq, cb, idx_f, out);
    } else {
        float* csq = (float*)d_ws;
        csq_kernel<<<KK / 4, 256, 0, stream>>>(cb, csq);
        argmin_fp32_kernel<<<dim3(TT / 128, BB), 256, 0, stream>>>(x, cb, csq, idx_f);
        gather_kernel<<<dim3(TT / 256, BB, 4), 256, 0, stream>>>(cb, idx_f, out);
    }
}